// Round 7
// baseline (252.380 us; speedup 1.0000x reference)
//
#include <hip/hip_runtime.h>
#include <hip/hip_fp16.h>
#include <stdint.h>

// ============================================================================
// Mix_Loss on MI355X.  R16 (from passing R15 @227.6us; k_pq_proto=65us #1):
//  R15 post-mortem: k_pq_proto occupancy-starved (512 blocks = 2/CU, LDS 37KB,
//  VALU 8.8%, BW 12%) -> latency-bound on LDS-atomic chains.
//  R16 k_pq_proto restructure (same numerics, same pacc scheme):
//   - 1024 blocks x 256 thr, 1 pixel/thread (grid -> 4 blocks/CU).
//   - No LDS transpose tile: thread owns full PQ row, writes 8x uint4 direct
//     (8 strided stores/row cover each 128B L2 line -> write-combine).
//   - Two-pass channels: pass1 ss (mu), pass2 reload m (L1-hot) + w,s; pack
//     4 channels at a time (pk live range 4 regs, VGPR ~64).
//   - LDS = pacc[800] only (3.2KB).
//  All other kernels byte-identical to R15.
// ============================================================================

#define NPIX  262144   // B*H*W = 4*256*256
#define NCLS  8
#define NQ    256
#define NNEG  256
#define NBLK  1024     // 256-pixel chunks for scan/place

typedef unsigned short u16;
typedef unsigned int   u32;

struct TFKeys { u32 k1[8][2], k2[8][2], k3[8][2]; };

// JAX threefry2x32 (20 rounds)
__host__ __device__ inline void tf2x32(u32 k0, u32 k1, u32 x0, u32 x1, u32& o0, u32& o1) {
  u32 ks2 = k0 ^ k1 ^ 0x1BD11BDAu;
  x0 += k0; x1 += k1;
#define TFR(R) { x0 += x1; x1 = (x1 << (R)) | (x1 >> (32 - (R))); x1 ^= x0; }
  TFR(13) TFR(15) TFR(26) TFR(6)
  x0 += k1;  x1 += ks2 + 1u;
  TFR(17) TFR(29) TFR(16) TFR(24)
  x0 += ks2; x1 += k0 + 2u;
  TFR(13) TFR(15) TFR(26) TFR(6)
  x0 += k0;  x1 += k1 + 3u;
  TFR(17) TFR(29) TFR(16) TFR(24)
  x0 += k1;  x1 += ks2 + 4u;
  TFR(13) TFR(15) TFR(26) TFR(6)
  x0 += ks2; x1 += k0 + 5u;
#undef TFR
  o0 = x0; o1 = x1;
}

__device__ inline float bfv(u16 v) { return __uint_as_float(((u32)v) << 16); }
__device__ inline float lo16(u32 v) { return __uint_as_float(v << 16); }
__device__ inline float hi16(u32 v) { return __uint_as_float(v & 0xFFFF0000u); }
__device__ inline float u01(u32 bits) { return __uint_as_float((bits >> 9) | 0x3F800000u) - 1.0f; }
__device__ inline u32 rbits(u32 k0, u32 k1, u32 idx) { u32 a, b; tf2x32(k0, k1, 0u, idx, a, b); return a ^ b; }
__device__ inline u32 packPQ(float p, float q) {
  return (u32)__half_as_ushort(__float2half(p)) | ((u32)__half_as_ushort(__float2half(q)) << 16);
}
__device__ inline float2 unpackPQ(u32 v) {
  return make_float2(__half2float(__ushort_as_half((u16)(v & 0xFFFFu))),
                     __half2float(__ushort_as_half((u16)(v >> 16))));
}
__device__ inline float frcp(float x) { return __builtin_amdgcn_rcpf(x); }

// ---------------------------------------------------------------------------
// R2 core + block-0 init fold (proven)
__global__ __launch_bounds__(256) void k_flags(const u16* __restrict__ lab, const u16* __restrict__ msk,
                                               const u16* __restrict__ prb, unsigned char* __restrict__ flags,
                                               int* __restrict__ blockCnt,
                                               float* __restrict__ protoAcc, float* __restrict__ ceAcc,
                                               int* __restrict__ diag) {
  __shared__ int cnt[16];
  int tid = threadIdx.x;
  if (blockIdx.x == 0) {
    for (int i = tid; i < 768; i += 256) protoAcc[i] = 0.f;
    if (tid < 8) ceAcc[tid] = 0.f;
    if (tid == 0) diag[0] = 0;
  }
  if (tid < 16) cnt[tid] = 0;
  __syncthreads();
  int n = blockIdx.x * 256 + tid;
  int b = n >> 16, hw = n & 65535;
  float m = bfv(msk[(b << 16) + hw]);
  int cls = 0; bool v = false;
  for (int s = 0; s < 8; s++) {
    float l = bfv(lab[((size_t)(b * 8 + s) << 16) + hw]);
    if (l * m > 0.f) { cls = s; v = true; }
  }
  bool h = false;
  if (v) { float p = bfv(prb[((size_t)(b * 8 + cls) << 16) + hw]); h = p < 0.97f; }
  flags[n] = (unsigned char)(cls | (v ? 16 : 0) | (h ? 32 : 0));
  if (v) atomicAdd(&cnt[cls], 1);
  if (h) atomicAdd(&cnt[8 + cls], 1);
  __syncthreads();
  if (tid < 16) blockCnt[tid * NBLK + blockIdx.x] = cnt[tid];
}

// ---------------------------------------------------------------------------
// R16 k_pq_proto: 1 pixel/thread, 1024 blocks. Direct PQ row write (no tile).
// pacc[8][100] LDS atomics + flush verbatim from proven R15.
__global__ __launch_bounds__(256) void k_pq_proto(const u16* __restrict__ mu, const u16* __restrict__ wgt,
                                                  const u16* __restrict__ sig,
                                                  const unsigned char* __restrict__ flags,
                                                  u32* __restrict__ PQ, float* __restrict__ protoAcc) {
  __shared__ float pacc[800];
  int t = threadIdx.x;
  pacc[t] = 0.f; pacc[t + 256] = 0.f; pacc[t + 512] = 0.f;
  if (t < 32) pacc[t + 768] = 0.f;
  __syncthreads();
  int n = blockIdx.x * 256 + t;
  int b = n >> 16, hw = n & 65535;
  size_t cb = (((size_t)(b * 32)) << 16) + hw;
  u32 f = flags[n];
  int cls = (int)(f & 7u);
  bool v = (f & 16u) != 0u;
  int base = cls * 100;
  // pass 1: per-pixel sum of squares over channels
  float ss = 0.f;
  #pragma unroll
  for (int c = 0; c < 32; c++) {
    float m = bfv(mu[cb + ((size_t)c << 16)]);
    ss += m * m;
  }
  float rn = 1.0f / fmaxf(sqrtf(ss), 1e-12f);
  // pass 2: reload m (L1-hot) + w,s; pack 4 channels -> uint4 store; proto atomics
  uint4* dst = (uint4*)(PQ + (size_t)n * 32);
  #pragma unroll
  for (int k = 0; k < 8; k++) {
    u32 pk[4];
    #pragma unroll
    for (int j = 0; j < 4; j++) {
      int c = 4 * k + j;
      float m = bfv(mu[cb + ((size_t)c << 16)]);
      float w = bfv(wgt[cb + ((size_t)c << 16)]);
      float s = bfv(sig[cb + ((size_t)c << 16)]);
      pk[j] = packPQ(m * rn * w, s * w);
      if (v) {
        float isw = w / s;                       // IEEE div (matches reference)
        atomicAdd(&pacc[base + c * 3 + 0], isw);
        atomicAdd(&pacc[base + c * 3 + 1], isw * m);
        atomicAdd(&pacc[base + c * 3 + 2], 1.0f / w);
      }
    }
    dst[k] = make_uint4(pk[0], pk[1], pk[2], pk[3]);
  }
  __syncthreads();
  // flush pacc -> protoAcc (layout [(s*32+c)*3+k] = s*96 + c*3 + k)
  for (int idx = t; idx < 800; idx += 256) {
    int c8 = idx / 100, rem = idx - c8 * 100;
    if (rem < 96) atomicAdd(&protoAcc[c8 * 96 + rem], pacc[idx]);
  }
}

// ---------------------------------------------------------------------------
// k_place + inline scan (R14-proven). Per block: exclusive prefix of
// blockCnt[ctr][0..blk-1]; block 0 writes counts[16]. Bit-identical to k_scan.
__global__ __launch_bounds__(256) void k_place(const unsigned char* __restrict__ flags,
                                               const int* __restrict__ blockCnt,
                                               int* __restrict__ tblV, int* __restrict__ tblH,
                                               int* __restrict__ counts) {
  __shared__ int wcnt[4][16];
  __shared__ int sOff[16], sTot[16];
  int tid = threadIdx.x;
  int blk = blockIdx.x;
  if (tid < 16) { sOff[tid] = 0; sTot[tid] = 0; }
  __syncthreads();
  {
    int ctr = tid & 15, seg = tid >> 4;              // 16 segs x 64 entries
    const int* row = blockCnt + ctr * NBLK + seg * 64;
    int lim = blk - seg * 64;                        // j < blk  <=>  l < lim
    int pre = 0, tot = 0;
    #pragma unroll 8
    for (int l = 0; l < 64; ++l) {
      int v = row[l];
      tot += v;
      pre += (l < lim) ? v : 0;
    }
    atomicAdd(&sOff[ctr], pre);
    if (blk == 0) atomicAdd(&sTot[ctr], tot);
  }
  __syncthreads();
  if (blk == 0 && tid < 16) counts[tid] = sTot[tid];
  // ---------------- original place body ----------------
  int n = blk * 256 + tid;
  int f = flags[n];
  int cls = f & 15; bool v = (f & 16) != 0, h = (f & 32) != 0;
  int wave = tid >> 6, lane = tid & 63;
  unsigned long long below = (1ull << lane) - 1ull;
  int rv = 0, rh = 0;
  for (int s = 0; s < 8; s++) {
    unsigned long long bv = __ballot(v && (cls == s));
    unsigned long long bh = __ballot(h && (cls == s));
    if (lane == 0) { wcnt[wave][s] = __popcll(bv); wcnt[wave][8 + s] = __popcll(bh); }
    if (cls == s) { rv = __popcll(bv & below); rh = __popcll(bh & below); }
  }
  __syncthreads();
  int preV = 0, preH = 0;
  for (int w2 = 0; w2 < wave; w2++) { preV += wcnt[w2][cls]; preH += wcnt[w2][8 + cls]; }
  if (v) tblV[(size_t)cls * NPIX + sOff[cls] + preV + rv] = n;
  if (h) tblH[(size_t)cls * NPIX + sOff[8 + cls] + preH + rh] = n;
}

// finalize prototypes + inter-prototype MLS logits; packed f16 protoPQ (R8, proven)
__global__ void k_protoFinal(const float* __restrict__ protoAcc, const int* __restrict__ counts,
                             u32* __restrict__ protoPQ, float* __restrict__ simL,
                             int* __restrict__ diag) {
  __shared__ float sP[256], sQ[256];
  __shared__ int alive;
  int tid = threadIdx.x;
  if (tid == 0) alive = 0;
  float a0 = protoAcc[tid * 3 + 0], a1 = protoAcc[tid * 3 + 1], a2 = protoAcc[tid * 3 + 2];
  bool have = counts[tid >> 5] > 0;
  bool ok = (a0 > 0.f) && (a2 > 0.f);
  __syncthreads();
  if (have && !ok) atomicOr(diag, 2);
  if (have && ok) alive = 1;
  float psig = 1.0f / a0;
  float pmu  = psig * a1;
  float pw   = 1.0f / a2;
  float sq = (have && ok) ? pmu * pmu : 0.f;
  #pragma unroll
  for (int d = 1; d < 32; d <<= 1) sq += __shfl_xor(sq, d);
  float rn = 1.0f / fmaxf(sqrtf(sq), 1e-12f);
  float pP = (have && ok) ? pmu * rn * pw : 0.f;
  float pQ = (have && ok) ? psig * pw : 0.f;
  sP[tid] = pP; sQ[tid] = pQ;
  protoPQ[tid] = packPQ(pP, pQ);
  __syncthreads();
  if (tid == 0 && alive == 0) atomicOr(diag, 32);
  if (tid < 64) {
    int i = tid >> 3, j = tid & 7;
    if (j < 7) {
      int o = (i + 1 + j) & 7;
      float acc = 0.f;
      for (int c = 0; c < 32; c++) {
        float d = sP[i * 32 + c] - sP[o * 32 + c];
        float dn = sQ[i * 32 + c] + sQ[o * 32 + c];
        acc += d * d / dn + logf(dn);
      }
      float sim = -0.5f * (acc * (1.0f / 32.0f));
      simL[i * 8 + j] = (counts[o] > 0) ? (sim * 2.0f) : -INFINITY;  // /TEMP(0.5)
    }
  }
}

// ---- R11 k_sample (proven 42.0us): anchor redundant on all threads; A-row
// direct from global (wave-uniform broadcast); fast __logf gumbel; rcp-mul MLS.
__global__ __launch_bounds__(256) void k_sample(TFKeys K, const float* __restrict__ simL,
                                                const int* __restrict__ counts,
                                                const int* __restrict__ tblV, const int* __restrict__ tblH,
                                                const u32* __restrict__ PQ, const u32* __restrict__ protoPQ,
                                                float* __restrict__ ceAcc, int* __restrict__ diag) {
  __shared__ float redM[4], redS[4];
  int blk = blockIdx.x;
  int i = blk >> 8, q = blk & 255;
  int t = threadIdx.x;
  u32 abits = rbits(K.k1[i][0], K.k1[i][1], (u32)q);
  float au = u01(abits);
  int hc = counts[8 + i];
  int ra = (int)(au * (float)hc);
  int cap = hc - 1; if (cap < 0) cap = 0;
  if (ra > cap) ra = cap; if (ra < 0) ra = 0;
  int ap = tblH[(size_t)i * NPIX + ra];
  if (ap < 0) ap = 0; if (ap > NPIX - 1) ap = NPIX - 1;
  const uint4* A4 = (const uint4*)(PQ + (size_t)ap * 32);
  u32 rem = (u32)(q * 256 + t);
  u32 k20 = K.k2[i][0], k21 = K.k2[i][1];
  float Lr[7];
  #pragma unroll
  for (int j = 0; j < 7; j++) Lr[j] = simL[i * 8 + j];
  float mg = 0.f; int pick = 0;
  #pragma unroll
  for (int j = 0; j < 7; j++) {
    u32 bits = rbits(k20, k21, rem * 7u + (u32)j);
    float f = u01(bits);
    float u = fmaxf(f, 1.17549435e-38f);
    float g = -__logf(-__logf(u));
    float v = g + Lr[j];
    if (j == 0) { mg = v; } else if (v > mg) { mg = v; pick = j; }
  }
  int nc = (i + 1 + pick) & 7;
  u32 bits3 = rbits(K.k3[i][0], K.k3[i][1], rem);
  float u3 = u01(bits3);
  int cntv = counts[nc];
  int rn = (int)(u3 * (float)cntv);
  int cap2 = cntv - 1; if (cap2 < 0) cap2 = 0;
  if (rn > cap2) rn = cap2; if (rn < 0) rn = 0;
  int np = tblV[(size_t)nc * NPIX + rn];
  if (np < 0) np = 0; if (np > NPIX - 1) np = NPIX - 1;
  const uint4* B = (const uint4*)(PQ + (size_t)np * 32);
  float accN = 0.f;
  #pragma unroll
  for (int k = 0; k < 8; k++) {
    uint4 ua = A4[k], ub = B[k];
    float2 fa, fb; float d, dn;
    fa = unpackPQ(ua.x); fb = unpackPQ(ub.x); d = fa.x - fb.x; dn = fa.y + fb.y; accN += d * d * frcp(dn) + __logf(dn);
    fa = unpackPQ(ua.y); fb = unpackPQ(ub.y); d = fa.x - fb.x; dn = fa.y + fb.y; accN += d * d * frcp(dn) + __logf(dn);
    fa = unpackPQ(ua.z); fb = unpackPQ(ub.z); d = fa.x - fb.x; dn = fa.y + fb.y; accN += d * d * frcp(dn) + __logf(dn);
    fa = unpackPQ(ua.w); fb = unpackPQ(ub.w); d = fa.x - fb.x; dn = fa.y + fb.y; accN += d * d * frcp(dn) + __logf(dn);
  }
  float lN = -(accN * (1.0f / 32.0f));
  float l0 = 0.f;
  if (t == 0) {
    const uint4* B0 = (const uint4*)(protoPQ + i * 32);
    float acc0 = 0.f;
    #pragma unroll
    for (int k = 0; k < 8; k++) {
      uint4 ua = A4[k], ub = B0[k];
      float2 fa, fb; float d, dn;
      fa = unpackPQ(ua.x); fb = unpackPQ(ub.x); d = fa.x - fb.x; dn = fa.y + fb.y; acc0 += d * d * frcp(dn) + __logf(dn);
      fa = unpackPQ(ua.y); fb = unpackPQ(ub.y); d = fa.x - fb.x; dn = fa.y + fb.y; acc0 += d * d * frcp(dn) + __logf(dn);
      fa = unpackPQ(ua.z); fb = unpackPQ(ub.z); d = fa.x - fb.x; dn = fa.y + fb.y; acc0 += d * d * frcp(dn) + __logf(dn);
      fa = unpackPQ(ua.w); fb = unpackPQ(ub.w); d = fa.x - fb.x; dn = fa.y + fb.y; acc0 += d * d * frcp(dn) + __logf(dn);
    }
    l0 = -(acc0 * (1.0f / 32.0f));
  }
  bool bad = !(lN == lN) || (t == 0 && !(l0 == l0));
  if (__ballot(bad) != 0ull && (t & 63) == 0) atomicOr(diag, 8);
  float lm = (t == 0) ? fmaxf(lN, l0) : lN;
  #pragma unroll
  for (int d = 1; d < 64; d <<= 1) lm = fmaxf(lm, __shfl_xor(lm, d));
  if ((t & 63) == 0) redM[t >> 6] = lm;
  __syncthreads();
  float M = fmaxf(fmaxf(redM[0], redM[1]), fmaxf(redM[2], redM[3]));
  float es = __expf(lN - M) + ((t == 0) ? __expf(l0 - M) : 0.f);
  #pragma unroll
  for (int d = 1; d < 64; d <<= 1) es += __shfl_xor(es, d);
  if ((t & 63) == 0) redS[t >> 6] = es;
  __syncthreads();
  if (t == 0) {
    float S = redS[0] + redS[1] + redS[2] + redS[3];
    float ce = (M + __logf(S)) - l0;
    atomicAdd(&ceAcc[i], ce);
  }
}

__global__ void k_final(const float* __restrict__ ceAcc, const int* __restrict__ counts,
                        const int* __restrict__ diag, u32* __restrict__ out) {
  if (blockIdx.x == 0 && threadIdx.x == 0) {
    float loss = 0.f; int vn = 0;
    int db = diag[0];
    for (int i = 0; i < 8; i++) {
      if (counts[i] > 0) vn++;
      float ce = ceAcc[i];
      if (counts[i] > 0 && counts[8 + i] > 0) {
        if (!(ce == ce)) db |= 4;
        loss += ce * (1.0f / 256.0f);
      }
    }
    if (vn == 0) db |= 1;
    loss = loss / (float)vn;
    if (!(loss == loss) && db == 0) db = 16;
    if (db != 0) loss = 4096.0f * (float)(1 + db);
    u32 fb = __float_as_uint(loss);
    u32 bv = (fb + 0x7FFFu + ((fb >> 16) & 1u)) >> 16;          // f32 -> bf16 RNE
    out[0] = (fb & 0xFFFF0000u) | (bv & 0xFFFFu);               // dual-decodable
  }
}

// ---------------------------------------------------------------------------
extern "C" void kernel_launch(void* const* d_in, const int* in_sizes, int n_in,
                              void* d_out, int out_size, void* d_ws, size_t ws_size,
                              hipStream_t stream) {
  (void)in_sizes; (void)n_in; (void)out_size; (void)ws_size;
  const u16* wgt = (const u16*)d_in[0];
  const u16* mu  = (const u16*)d_in[1];
  const u16* sig = (const u16*)d_in[2];
  const u16* lab = (const u16*)d_in[3];
  const u16* msk = (const u16*)d_in[4];
  const u16* prb = (const u16*)d_in[5];

  // workspace carve (256B-aligned); total ~49 MB
  char* wp = (char*)d_ws;
  auto take = [&](size_t bytes) -> void* { void* p = (void*)wp; wp += ((bytes + 255) & ~(size_t)255); return p; };
  u32*   PQ       = (u32*)  take((size_t)NPIX * 32 * 4);
  int*   tblV     = (int*)  take((size_t)NCLS * NPIX * 4);
  int*   tblH     = (int*)  take((size_t)NCLS * NPIX * 4);
  unsigned char* flags = (unsigned char*)take(NPIX);
  int*   blockCnt = (int*)  take(16 * NBLK * 4);
  float* protoAcc = (float*)take(768 * 4);
  u32*   protoPQ  = (u32*)  take(256 * 4);
  float* simL     = (float*)take(64 * 4);
  int*   counts   = (int*)  take(16 * 4);
  float* ceAcc    = (float*)take(8 * 4);
  int*   diag     = (int*)  take(4);

  // Host-side JAX key derivation (partitionable/fold-like split)
  TFKeys K;
  for (u32 i = 0; i < 8; i++) {
    u32 ki0, ki1;
    tf2x32(0u, 42u, 0u, i, ki0, ki1);
    tf2x32(ki0, ki1, 0u, 0u, K.k1[i][0], K.k1[i][1]);
    tf2x32(ki0, ki1, 0u, 1u, K.k2[i][0], K.k2[i][1]);
    tf2x32(ki0, ki1, 0u, 2u, K.k3[i][0], K.k3[i][1]);
  }

  k_flags<<<1024, 256, 0, stream>>>(lab, msk, prb, flags, blockCnt, protoAcc, ceAcc, diag);
  k_pq_proto<<<1024, 256, 0, stream>>>(mu, wgt, sig, flags, PQ, protoAcc);
  k_place<<<1024, 256, 0, stream>>>(flags, blockCnt, tblV, tblH, counts);
  k_protoFinal<<<1, 256, 0, stream>>>(protoAcc, counts, protoPQ, simL, diag);
  k_sample<<<2048, 256, 0, stream>>>(K, simL, counts, tblV, tblH, PQ, protoPQ, ceAcc, diag);
  k_final<<<1, 64, 0, stream>>>(ceAcc, counts, diag, (u32*)d_out);
}

// Round 8
// 233.861 us; speedup vs baseline: 1.0792x; 1.0792x over previous
//
#include <hip/hip_runtime.h>
#include <hip/hip_fp16.h>
#include <stdint.h>

// ============================================================================
// Mix_Loss on MI355X.  R17 (from R16 @252.4 regression; best = R15 @227.6):
//  R16 post-mortem: direct strided uint4 stores leaked partial lines
//  (WRITE_SIZE 34->78MB) -> keep R15's LDS transpose tile (proven full-line
//  writes) AND R16's occupancy fix (grid 512->1024):
//  R17 k_pq_proto: 1024 blocks x 256 thr, 1 pixel/thread, ONE tile phase.
//   - m[32] in regs (ss pass), per-channel w,s load -> pack to tile[t*33+c]
//     (33-stride conflict-free, proven) + pacc atomics verbatim R15.
//   - block uint4 copy-out (proven R8 coalescing); pacc flush.
//   - LDS 37KB -> 4 blocks/CU; grid 1024 = exactly 4/CU (vs R15's 2/CU).
//  All other kernels byte-identical to R15 (passed).
// ============================================================================

#define NPIX  262144   // B*H*W = 4*256*256
#define NCLS  8
#define NQ    256
#define NNEG  256
#define NBLK  1024     // 256-pixel chunks for scan/place

typedef unsigned short u16;
typedef unsigned int   u32;

struct TFKeys { u32 k1[8][2], k2[8][2], k3[8][2]; };

// JAX threefry2x32 (20 rounds)
__host__ __device__ inline void tf2x32(u32 k0, u32 k1, u32 x0, u32 x1, u32& o0, u32& o1) {
  u32 ks2 = k0 ^ k1 ^ 0x1BD11BDAu;
  x0 += k0; x1 += k1;
#define TFR(R) { x0 += x1; x1 = (x1 << (R)) | (x1 >> (32 - (R))); x1 ^= x0; }
  TFR(13) TFR(15) TFR(26) TFR(6)
  x0 += k1;  x1 += ks2 + 1u;
  TFR(17) TFR(29) TFR(16) TFR(24)
  x0 += ks2; x1 += k0 + 2u;
  TFR(13) TFR(15) TFR(26) TFR(6)
  x0 += k0;  x1 += k1 + 3u;
  TFR(17) TFR(29) TFR(16) TFR(24)
  x0 += k1;  x1 += ks2 + 4u;
  TFR(13) TFR(15) TFR(26) TFR(6)
  x0 += ks2; x1 += k0 + 5u;
#undef TFR
  o0 = x0; o1 = x1;
}

__device__ inline float bfv(u16 v) { return __uint_as_float(((u32)v) << 16); }
__device__ inline float lo16(u32 v) { return __uint_as_float(v << 16); }
__device__ inline float hi16(u32 v) { return __uint_as_float(v & 0xFFFF0000u); }
__device__ inline float u01(u32 bits) { return __uint_as_float((bits >> 9) | 0x3F800000u) - 1.0f; }
__device__ inline u32 rbits(u32 k0, u32 k1, u32 idx) { u32 a, b; tf2x32(k0, k1, 0u, idx, a, b); return a ^ b; }
__device__ inline u32 packPQ(float p, float q) {
  return (u32)__half_as_ushort(__float2half(p)) | ((u32)__half_as_ushort(__float2half(q)) << 16);
}
__device__ inline float2 unpackPQ(u32 v) {
  return make_float2(__half2float(__ushort_as_half((u16)(v & 0xFFFFu))),
                     __half2float(__ushort_as_half((u16)(v >> 16))));
}
__device__ inline float frcp(float x) { return __builtin_amdgcn_rcpf(x); }

// ---------------------------------------------------------------------------
// R2 core + block-0 init fold (proven)
__global__ __launch_bounds__(256) void k_flags(const u16* __restrict__ lab, const u16* __restrict__ msk,
                                               const u16* __restrict__ prb, unsigned char* __restrict__ flags,
                                               int* __restrict__ blockCnt,
                                               float* __restrict__ protoAcc, float* __restrict__ ceAcc,
                                               int* __restrict__ diag) {
  __shared__ int cnt[16];
  int tid = threadIdx.x;
  if (blockIdx.x == 0) {
    for (int i = tid; i < 768; i += 256) protoAcc[i] = 0.f;
    if (tid < 8) ceAcc[tid] = 0.f;
    if (tid == 0) diag[0] = 0;
  }
  if (tid < 16) cnt[tid] = 0;
  __syncthreads();
  int n = blockIdx.x * 256 + tid;
  int b = n >> 16, hw = n & 65535;
  float m = bfv(msk[(b << 16) + hw]);
  int cls = 0; bool v = false;
  for (int s = 0; s < 8; s++) {
    float l = bfv(lab[((size_t)(b * 8 + s) << 16) + hw]);
    if (l * m > 0.f) { cls = s; v = true; }
  }
  bool h = false;
  if (v) { float p = bfv(prb[((size_t)(b * 8 + cls) << 16) + hw]); h = p < 0.97f; }
  flags[n] = (unsigned char)(cls | (v ? 16 : 0) | (h ? 32 : 0));
  if (v) atomicAdd(&cnt[cls], 1);
  if (h) atomicAdd(&cnt[8 + cls], 1);
  __syncthreads();
  if (tid < 16) blockCnt[tid * NBLK + blockIdx.x] = cnt[tid];
}

// ---------------------------------------------------------------------------
// R17 k_pq_proto: 1 pixel/thread, 1024 blocks, LDS transpose tile (proven
// write coalescing) + pacc[8][100] atomics verbatim R15.
__global__ __launch_bounds__(256) void k_pq_proto(const u16* __restrict__ mu, const u16* __restrict__ wgt,
                                                  const u16* __restrict__ sig,
                                                  const unsigned char* __restrict__ flags,
                                                  u32* __restrict__ PQ, float* __restrict__ protoAcc) {
  __shared__ u32 tile[256 * 33];
  __shared__ float pacc[800];
  int t = threadIdx.x;
  pacc[t] = 0.f; pacc[t + 256] = 0.f; pacc[t + 512] = 0.f;
  if (t < 32) pacc[t + 768] = 0.f;
  __syncthreads();
  int n0 = blockIdx.x * 256;
  int n = n0 + t;
  int b = n >> 16, hw = n & 65535;
  size_t cb = (((size_t)(b * 32)) << 16) + hw;
  u32 f = flags[n];
  int cls = (int)(f & 7u);
  bool v = (f & 16u) != 0u;
  int base = cls * 100;
  // pass 1: mu into registers + sum of squares
  float m[32];
  float ss = 0.f;
  #pragma unroll
  for (int c = 0; c < 32; c++) {
    m[c] = bfv(mu[cb + ((size_t)c << 16)]);
    ss += m[c] * m[c];
  }
  float rn = 1.0f / fmaxf(sqrtf(ss), 1e-12f);
  // pass 2: w,s loads; pack into tile; proto atomics (verbatim R15 scheme)
  #pragma unroll
  for (int c = 0; c < 32; c++) {
    float w = bfv(wgt[cb + ((size_t)c << 16)]);
    float s = bfv(sig[cb + ((size_t)c << 16)]);
    tile[t * 33 + c] = packPQ(m[c] * rn * w, s * w);
    if (v) {
      float isw = w / s;                         // IEEE div (matches reference)
      atomicAdd(&pacc[base + c * 3 + 0], isw);
      atomicAdd(&pacc[base + c * 3 + 1], isw * m[c]);
      atomicAdd(&pacc[base + c * 3 + 2], 1.0f / w);
    }
  }
  __syncthreads();
  // coalesced copy-out (proven R8 pattern)
  uint4* dst = (uint4*)(PQ + (size_t)n0 * 32);
  for (int k = t; k < 2048; k += 256) {
    int p = k >> 3, c4 = (k & 7) * 4;
    dst[k] = make_uint4(tile[p * 33 + c4], tile[p * 33 + c4 + 1],
                        tile[p * 33 + c4 + 2], tile[p * 33 + c4 + 3]);
  }
  // flush pacc -> protoAcc (pacc final since before the barrier)
  for (int idx = t; idx < 800; idx += 256) {
    int c8 = idx / 100, rem = idx - c8 * 100;
    if (rem < 96) atomicAdd(&protoAcc[c8 * 96 + rem], pacc[idx]);
  }
}

// ---------------------------------------------------------------------------
// k_place + inline scan (R14-proven). Per block: exclusive prefix of
// blockCnt[ctr][0..blk-1]; block 0 writes counts[16]. Bit-identical to k_scan.
__global__ __launch_bounds__(256) void k_place(const unsigned char* __restrict__ flags,
                                               const int* __restrict__ blockCnt,
                                               int* __restrict__ tblV, int* __restrict__ tblH,
                                               int* __restrict__ counts) {
  __shared__ int wcnt[4][16];
  __shared__ int sOff[16], sTot[16];
  int tid = threadIdx.x;
  int blk = blockIdx.x;
  if (tid < 16) { sOff[tid] = 0; sTot[tid] = 0; }
  __syncthreads();
  {
    int ctr = tid & 15, seg = tid >> 4;              // 16 segs x 64 entries
    const int* row = blockCnt + ctr * NBLK + seg * 64;
    int lim = blk - seg * 64;                        // j < blk  <=>  l < lim
    int pre = 0, tot = 0;
    #pragma unroll 8
    for (int l = 0; l < 64; ++l) {
      int v = row[l];
      tot += v;
      pre += (l < lim) ? v : 0;
    }
    atomicAdd(&sOff[ctr], pre);
    if (blk == 0) atomicAdd(&sTot[ctr], tot);
  }
  __syncthreads();
  if (blk == 0 && tid < 16) counts[tid] = sTot[tid];
  // ---------------- original place body ----------------
  int n = blk * 256 + tid;
  int f = flags[n];
  int cls = f & 15; bool v = (f & 16) != 0, h = (f & 32) != 0;
  int wave = tid >> 6, lane = tid & 63;
  unsigned long long below = (1ull << lane) - 1ull;
  int rv = 0, rh = 0;
  for (int s = 0; s < 8; s++) {
    unsigned long long bv = __ballot(v && (cls == s));
    unsigned long long bh = __ballot(h && (cls == s));
    if (lane == 0) { wcnt[wave][s] = __popcll(bv); wcnt[wave][8 + s] = __popcll(bh); }
    if (cls == s) { rv = __popcll(bv & below); rh = __popcll(bh & below); }
  }
  __syncthreads();
  int preV = 0, preH = 0;
  for (int w2 = 0; w2 < wave; w2++) { preV += wcnt[w2][cls]; preH += wcnt[w2][8 + cls]; }
  if (v) tblV[(size_t)cls * NPIX + sOff[cls] + preV + rv] = n;
  if (h) tblH[(size_t)cls * NPIX + sOff[8 + cls] + preH + rh] = n;
}

// finalize prototypes + inter-prototype MLS logits; packed f16 protoPQ (R8, proven)
__global__ void k_protoFinal(const float* __restrict__ protoAcc, const int* __restrict__ counts,
                             u32* __restrict__ protoPQ, float* __restrict__ simL,
                             int* __restrict__ diag) {
  __shared__ float sP[256], sQ[256];
  __shared__ int alive;
  int tid = threadIdx.x;
  if (tid == 0) alive = 0;
  float a0 = protoAcc[tid * 3 + 0], a1 = protoAcc[tid * 3 + 1], a2 = protoAcc[tid * 3 + 2];
  bool have = counts[tid >> 5] > 0;
  bool ok = (a0 > 0.f) && (a2 > 0.f);
  __syncthreads();
  if (have && !ok) atomicOr(diag, 2);
  if (have && ok) alive = 1;
  float psig = 1.0f / a0;
  float pmu  = psig * a1;
  float pw   = 1.0f / a2;
  float sq = (have && ok) ? pmu * pmu : 0.f;
  #pragma unroll
  for (int d = 1; d < 32; d <<= 1) sq += __shfl_xor(sq, d);
  float rn = 1.0f / fmaxf(sqrtf(sq), 1e-12f);
  float pP = (have && ok) ? pmu * rn * pw : 0.f;
  float pQ = (have && ok) ? psig * pw : 0.f;
  sP[tid] = pP; sQ[tid] = pQ;
  protoPQ[tid] = packPQ(pP, pQ);
  __syncthreads();
  if (tid == 0 && alive == 0) atomicOr(diag, 32);
  if (tid < 64) {
    int i = tid >> 3, j = tid & 7;
    if (j < 7) {
      int o = (i + 1 + j) & 7;
      float acc = 0.f;
      for (int c = 0; c < 32; c++) {
        float d = sP[i * 32 + c] - sP[o * 32 + c];
        float dn = sQ[i * 32 + c] + sQ[o * 32 + c];
        acc += d * d / dn + logf(dn);
      }
      float sim = -0.5f * (acc * (1.0f / 32.0f));
      simL[i * 8 + j] = (counts[o] > 0) ? (sim * 2.0f) : -INFINITY;  // /TEMP(0.5)
    }
  }
}

// ---- R11 k_sample (proven 42.0us): anchor redundant on all threads; A-row
// direct from global (wave-uniform broadcast); fast __logf gumbel; rcp-mul MLS.
__global__ __launch_bounds__(256) void k_sample(TFKeys K, const float* __restrict__ simL,
                                                const int* __restrict__ counts,
                                                const int* __restrict__ tblV, const int* __restrict__ tblH,
                                                const u32* __restrict__ PQ, const u32* __restrict__ protoPQ,
                                                float* __restrict__ ceAcc, int* __restrict__ diag) {
  __shared__ float redM[4], redS[4];
  int blk = blockIdx.x;
  int i = blk >> 8, q = blk & 255;
  int t = threadIdx.x;
  u32 abits = rbits(K.k1[i][0], K.k1[i][1], (u32)q);
  float au = u01(abits);
  int hc = counts[8 + i];
  int ra = (int)(au * (float)hc);
  int cap = hc - 1; if (cap < 0) cap = 0;
  if (ra > cap) ra = cap; if (ra < 0) ra = 0;
  int ap = tblH[(size_t)i * NPIX + ra];
  if (ap < 0) ap = 0; if (ap > NPIX - 1) ap = NPIX - 1;
  const uint4* A4 = (const uint4*)(PQ + (size_t)ap * 32);
  u32 rem = (u32)(q * 256 + t);
  u32 k20 = K.k2[i][0], k21 = K.k2[i][1];
  float Lr[7];
  #pragma unroll
  for (int j = 0; j < 7; j++) Lr[j] = simL[i * 8 + j];
  float mg = 0.f; int pick = 0;
  #pragma unroll
  for (int j = 0; j < 7; j++) {
    u32 bits = rbits(k20, k21, rem * 7u + (u32)j);
    float f = u01(bits);
    float u = fmaxf(f, 1.17549435e-38f);
    float g = -__logf(-__logf(u));
    float v = g + Lr[j];
    if (j == 0) { mg = v; } else if (v > mg) { mg = v; pick = j; }
  }
  int nc = (i + 1 + pick) & 7;
  u32 bits3 = rbits(K.k3[i][0], K.k3[i][1], rem);
  float u3 = u01(bits3);
  int cntv = counts[nc];
  int rn = (int)(u3 * (float)cntv);
  int cap2 = cntv - 1; if (cap2 < 0) cap2 = 0;
  if (rn > cap2) rn = cap2; if (rn < 0) rn = 0;
  int np = tblV[(size_t)nc * NPIX + rn];
  if (np < 0) np = 0; if (np > NPIX - 1) np = NPIX - 1;
  const uint4* B = (const uint4*)(PQ + (size_t)np * 32);
  float accN = 0.f;
  #pragma unroll
  for (int k = 0; k < 8; k++) {
    uint4 ua = A4[k], ub = B[k];
    float2 fa, fb; float d, dn;
    fa = unpackPQ(ua.x); fb = unpackPQ(ub.x); d = fa.x - fb.x; dn = fa.y + fb.y; accN += d * d * frcp(dn) + __logf(dn);
    fa = unpackPQ(ua.y); fb = unpackPQ(ub.y); d = fa.x - fb.x; dn = fa.y + fb.y; accN += d * d * frcp(dn) + __logf(dn);
    fa = unpackPQ(ua.z); fb = unpackPQ(ub.z); d = fa.x - fb.x; dn = fa.y + fb.y; accN += d * d * frcp(dn) + __logf(dn);
    fa = unpackPQ(ua.w); fb = unpackPQ(ub.w); d = fa.x - fb.x; dn = fa.y + fb.y; accN += d * d * frcp(dn) + __logf(dn);
  }
  float lN = -(accN * (1.0f / 32.0f));
  float l0 = 0.f;
  if (t == 0) {
    const uint4* B0 = (const uint4*)(protoPQ + i * 32);
    float acc0 = 0.f;
    #pragma unroll
    for (int k = 0; k < 8; k++) {
      uint4 ua = A4[k], ub = B0[k];
      float2 fa, fb; float d, dn;
      fa = unpackPQ(ua.x); fb = unpackPQ(ub.x); d = fa.x - fb.x; dn = fa.y + fb.y; acc0 += d * d * frcp(dn) + __logf(dn);
      fa = unpackPQ(ua.y); fb = unpackPQ(ub.y); d = fa.x - fb.x; dn = fa.y + fb.y; acc0 += d * d * frcp(dn) + __logf(dn);
      fa = unpackPQ(ua.z); fb = unpackPQ(ub.z); d = fa.x - fb.x; dn = fa.y + fb.y; acc0 += d * d * frcp(dn) + __logf(dn);
      fa = unpackPQ(ua.w); fb = unpackPQ(ub.w); d = fa.x - fb.x; dn = fa.y + fb.y; acc0 += d * d * frcp(dn) + __logf(dn);
    }
    l0 = -(acc0 * (1.0f / 32.0f));
  }
  bool bad = !(lN == lN) || (t == 0 && !(l0 == l0));
  if (__ballot(bad) != 0ull && (t & 63) == 0) atomicOr(diag, 8);
  float lm = (t == 0) ? fmaxf(lN, l0) : lN;
  #pragma unroll
  for (int d = 1; d < 64; d <<= 1) lm = fmaxf(lm, __shfl_xor(lm, d));
  if ((t & 63) == 0) redM[t >> 6] = lm;
  __syncthreads();
  float M = fmaxf(fmaxf(redM[0], redM[1]), fmaxf(redM[2], redM[3]));
  float es = __expf(lN - M) + ((t == 0) ? __expf(l0 - M) : 0.f);
  #pragma unroll
  for (int d = 1; d < 64; d <<= 1) es += __shfl_xor(es, d);
  if ((t & 63) == 0) redS[t >> 6] = es;
  __syncthreads();
  if (t == 0) {
    float S = redS[0] + redS[1] + redS[2] + redS[3];
    float ce = (M + __logf(S)) - l0;
    atomicAdd(&ceAcc[i], ce);
  }
}

__global__ void k_final(const float* __restrict__ ceAcc, const int* __restrict__ counts,
                        const int* __restrict__ diag, u32* __restrict__ out) {
  if (blockIdx.x == 0 && threadIdx.x == 0) {
    float loss = 0.f; int vn = 0;
    int db = diag[0];
    for (int i = 0; i < 8; i++) {
      if (counts[i] > 0) vn++;
      float ce = ceAcc[i];
      if (counts[i] > 0 && counts[8 + i] > 0) {
        if (!(ce == ce)) db |= 4;
        loss += ce * (1.0f / 256.0f);
      }
    }
    if (vn == 0) db |= 1;
    loss = loss / (float)vn;
    if (!(loss == loss) && db == 0) db = 16;
    if (db != 0) loss = 4096.0f * (float)(1 + db);
    u32 fb = __float_as_uint(loss);
    u32 bv = (fb + 0x7FFFu + ((fb >> 16) & 1u)) >> 16;          // f32 -> bf16 RNE
    out[0] = (fb & 0xFFFF0000u) | (bv & 0xFFFFu);               // dual-decodable
  }
}

// ---------------------------------------------------------------------------
extern "C" void kernel_launch(void* const* d_in, const int* in_sizes, int n_in,
                              void* d_out, int out_size, void* d_ws, size_t ws_size,
                              hipStream_t stream) {
  (void)in_sizes; (void)n_in; (void)out_size; (void)ws_size;
  const u16* wgt = (const u16*)d_in[0];
  const u16* mu  = (const u16*)d_in[1];
  const u16* sig = (const u16*)d_in[2];
  const u16* lab = (const u16*)d_in[3];
  const u16* msk = (const u16*)d_in[4];
  const u16* prb = (const u16*)d_in[5];

  // workspace carve (256B-aligned); total ~49 MB
  char* wp = (char*)d_ws;
  auto take = [&](size_t bytes) -> void* { void* p = (void*)wp; wp += ((bytes + 255) & ~(size_t)255); return p; };
  u32*   PQ       = (u32*)  take((size_t)NPIX * 32 * 4);
  int*   tblV     = (int*)  take((size_t)NCLS * NPIX * 4);
  int*   tblH     = (int*)  take((size_t)NCLS * NPIX * 4);
  unsigned char* flags = (unsigned char*)take(NPIX);
  int*   blockCnt = (int*)  take(16 * NBLK * 4);
  float* protoAcc = (float*)take(768 * 4);
  u32*   protoPQ  = (u32*)  take(256 * 4);
  float* simL     = (float*)take(64 * 4);
  int*   counts   = (int*)  take(16 * 4);
  float* ceAcc    = (float*)take(8 * 4);
  int*   diag     = (int*)  take(4);

  // Host-side JAX key derivation (partitionable/fold-like split)
  TFKeys K;
  for (u32 i = 0; i < 8; i++) {
    u32 ki0, ki1;
    tf2x32(0u, 42u, 0u, i, ki0, ki1);
    tf2x32(ki0, ki1, 0u, 0u, K.k1[i][0], K.k1[i][1]);
    tf2x32(ki0, ki1, 0u, 1u, K.k2[i][0], K.k2[i][1]);
    tf2x32(ki0, ki1, 0u, 2u, K.k3[i][0], K.k3[i][1]);
  }

  k_flags<<<1024, 256, 0, stream>>>(lab, msk, prb, flags, blockCnt, protoAcc, ceAcc, diag);
  k_pq_proto<<<1024, 256, 0, stream>>>(mu, wgt, sig, flags, PQ, protoAcc);
  k_place<<<1024, 256, 0, stream>>>(flags, blockCnt, tblV, tblH, counts);
  k_protoFinal<<<1, 256, 0, stream>>>(protoAcc, counts, protoPQ, simL, diag);
  k_sample<<<2048, 256, 0, stream>>>(K, simL, counts, tblV, tblH, PQ, protoPQ, ceAcc, diag);
  k_final<<<1, 64, 0, stream>>>(ceAcc, counts, diag, (u32*)d_out);
}

// Round 9
// 225.593 us; speedup vs baseline: 1.1187x; 1.0366x over previous
//
#include <hip/hip_runtime.h>
#include <hip/hip_fp16.h>
#include <stdint.h>

// ============================================================================
// Mix_Loss on MI355X.  R18 (from R17 @233.9; best = R15 @227.6):
//  R15/R17 post-mortem: k_pq_proto's +40us over plain k_pq is LDS-atomic PIPE
//  occupancy: ~6 lanes/wave share each (cls,c,k) address -> ds_add_f32
//  serializes ~6-way; 8 waves x 192 insts x ~75cy ~= 48us/CU. Occupancy can't
//  hide a shared-pipe serialization.
//  R18 = R15 byte-identical EXCEPT pacc is 4-way replicated by (lane&3) with
//  copy stride 808 (808%32=8 -> copies on distinct banks): conflict ~6 -> ~1.5.
//  Flush pre-reduces 4 copies then same 768 global atomics.
//  Predicted k_pq_proto 65 -> ~35-45us; total ~200-210us.
// ============================================================================

#define NPIX  262144   // B*H*W = 4*256*256
#define NCLS  8
#define NQ    256
#define NNEG  256
#define NBLK  1024     // 256-pixel chunks for scan/place

typedef unsigned short u16;
typedef unsigned int   u32;

struct TFKeys { u32 k1[8][2], k2[8][2], k3[8][2]; };

// JAX threefry2x32 (20 rounds)
__host__ __device__ inline void tf2x32(u32 k0, u32 k1, u32 x0, u32 x1, u32& o0, u32& o1) {
  u32 ks2 = k0 ^ k1 ^ 0x1BD11BDAu;
  x0 += k0; x1 += k1;
#define TFR(R) { x0 += x1; x1 = (x1 << (R)) | (x1 >> (32 - (R))); x1 ^= x0; }
  TFR(13) TFR(15) TFR(26) TFR(6)
  x0 += k1;  x1 += ks2 + 1u;
  TFR(17) TFR(29) TFR(16) TFR(24)
  x0 += ks2; x1 += k0 + 2u;
  TFR(13) TFR(15) TFR(26) TFR(6)
  x0 += k0;  x1 += k1 + 3u;
  TFR(17) TFR(29) TFR(16) TFR(24)
  x0 += k1;  x1 += ks2 + 4u;
  TFR(13) TFR(15) TFR(26) TFR(6)
  x0 += ks2; x1 += k0 + 5u;
#undef TFR
  o0 = x0; o1 = x1;
}

__device__ inline float bfv(u16 v) { return __uint_as_float(((u32)v) << 16); }
__device__ inline float lo16(u32 v) { return __uint_as_float(v << 16); }
__device__ inline float hi16(u32 v) { return __uint_as_float(v & 0xFFFF0000u); }
__device__ inline float u01(u32 bits) { return __uint_as_float((bits >> 9) | 0x3F800000u) - 1.0f; }
__device__ inline u32 rbits(u32 k0, u32 k1, u32 idx) { u32 a, b; tf2x32(k0, k1, 0u, idx, a, b); return a ^ b; }
__device__ inline u32 packPQ(float p, float q) {
  return (u32)__half_as_ushort(__float2half(p)) | ((u32)__half_as_ushort(__float2half(q)) << 16);
}
__device__ inline float2 unpackPQ(u32 v) {
  return make_float2(__half2float(__ushort_as_half((u16)(v & 0xFFFFu))),
                     __half2float(__ushort_as_half((u16)(v >> 16))));
}
__device__ inline float frcp(float x) { return __builtin_amdgcn_rcpf(x); }

// ---------------------------------------------------------------------------
// R2 core + block-0 init fold (proven)
__global__ __launch_bounds__(256) void k_flags(const u16* __restrict__ lab, const u16* __restrict__ msk,
                                               const u16* __restrict__ prb, unsigned char* __restrict__ flags,
                                               int* __restrict__ blockCnt,
                                               float* __restrict__ protoAcc, float* __restrict__ ceAcc,
                                               int* __restrict__ diag) {
  __shared__ int cnt[16];
  int tid = threadIdx.x;
  if (blockIdx.x == 0) {
    for (int i = tid; i < 768; i += 256) protoAcc[i] = 0.f;
    if (tid < 8) ceAcc[tid] = 0.f;
    if (tid == 0) diag[0] = 0;
  }
  if (tid < 16) cnt[tid] = 0;
  __syncthreads();
  int n = blockIdx.x * 256 + tid;
  int b = n >> 16, hw = n & 65535;
  float m = bfv(msk[(b << 16) + hw]);
  int cls = 0; bool v = false;
  for (int s = 0; s < 8; s++) {
    float l = bfv(lab[((size_t)(b * 8 + s) << 16) + hw]);
    if (l * m > 0.f) { cls = s; v = true; }
  }
  bool h = false;
  if (v) { float p = bfv(prb[((size_t)(b * 8 + cls) << 16) + hw]); h = p < 0.97f; }
  flags[n] = (unsigned char)(cls | (v ? 16 : 0) | (h ? 32 : 0));
  if (v) atomicAdd(&cnt[cls], 1);
  if (h) atomicAdd(&cnt[8 + cls], 1);
  __syncthreads();
  if (tid < 16) blockCnt[tid * NBLK + blockIdx.x] = cnt[tid];
}

// ---------------------------------------------------------------------------
// R18 k_pq_proto: R15 body (512 blocks, 2 pixels/thread, u32 loads, LDS
// transpose tile) with 4-way replicated pacc (copy = lane&3, stride 808).
__global__ __launch_bounds__(256) void k_pq_proto(const u16* __restrict__ mu, const u16* __restrict__ wgt,
                                                  const u16* __restrict__ sig,
                                                  const unsigned char* __restrict__ flags,
                                                  u32* __restrict__ PQ, float* __restrict__ protoAcc) {
  __shared__ u32 tile[256 * 33];
  __shared__ float pacc[4 * 808];
  int t = threadIdx.x;
  for (int i = t; i < 4 * 808; i += 256) pacc[i] = 0.f;
  __syncthreads();
  int n0 = blockIdx.x * 512;
  int b = n0 >> 16;
  int hwt = (n0 & 65535) + 2 * t;
  size_t cb = ((size_t)(b * 32)) << 16;
  // flags for this thread's two pixels
  u32 f2 = *(const u16*)(flags + n0 + 2 * t);
  int cls0 = (int)(f2 & 7u);         bool v0 = (f2 & 16u) != 0u;
  int cls1 = (int)((f2 >> 8) & 7u);  bool v1 = ((f2 >> 8) & 16u) != 0u;
  int copy = (t & 3) * 808;
  int base0 = copy + cls0 * 100, base1 = copy + cls1 * 100;
  u32 m2[32];
  float ss0 = 0.f, ss1 = 0.f;
  #pragma unroll
  for (int c = 0; c < 32; c++) {
    m2[c] = *(const u32*)(mu + cb + ((size_t)c << 16) + hwt);
    float a = lo16(m2[c]), d = hi16(m2[c]);
    ss0 += a * a; ss1 += d * d;
  }
  float rn0 = 1.0f / fmaxf(sqrtf(ss0), 1e-12f);
  float rn1 = 1.0f / fmaxf(sqrtf(ss1), 1e-12f);
  u32 pk0[32], pk1[32];
  #pragma unroll
  for (int c = 0; c < 32; c++) {
    u32 w2 = *(const u32*)(wgt + cb + ((size_t)c << 16) + hwt);
    u32 s2 = *(const u32*)(sig + cb + ((size_t)c << 16) + hwt);
    float wl = lo16(w2), wh = hi16(w2);
    float sl = lo16(s2), sh = hi16(s2);
    float ml = lo16(m2[c]), mh = hi16(m2[c]);
    pk0[c] = packPQ(ml * rn0 * wl, sl * wl);
    pk1[c] = packPQ(mh * rn1 * wh, sh * wh);
    if (v0) {
      float isw = wl / sl;                       // IEEE div (matches reference)
      atomicAdd(&pacc[base0 + c * 3 + 0], isw);
      atomicAdd(&pacc[base0 + c * 3 + 1], isw * ml);
      atomicAdd(&pacc[base0 + c * 3 + 2], 1.0f / wl);
    }
    if (v1) {
      float isw = wh / sh;
      atomicAdd(&pacc[base1 + c * 3 + 0], isw);
      atomicAdd(&pacc[base1 + c * 3 + 1], isw * mh);
      atomicAdd(&pacc[base1 + c * 3 + 2], 1.0f / wh);
    }
  }
  // PQ transpose + write (verbatim R8)
  #pragma unroll
  for (int ch = 0; ch < 2; ch++) {
    if ((t >> 7) == ch) {
      int l = t & 127;
      #pragma unroll
      for (int c = 0; c < 32; c++) {
        tile[(2 * l + 0) * 33 + c] = pk0[c];
        tile[(2 * l + 1) * 33 + c] = pk1[c];
      }
    }
    __syncthreads();
    uint4* dst = (uint4*)(PQ + (size_t)(n0 + ch * 256) * 32);
    for (int k = t; k < 2048; k += 256) {
      int p = k >> 3, c4 = (k & 7) * 4;
      dst[k] = make_uint4(tile[p * 33 + c4], tile[p * 33 + c4 + 1],
                          tile[p * 33 + c4 + 2], tile[p * 33 + c4 + 3]);
    }
    __syncthreads();
  }
  // flush: pre-reduce 4 copies, then global atomics (same 768 bins as R15)
  for (int idx = t; idx < 800; idx += 256) {
    int c8 = idx / 100, rem = idx - c8 * 100;
    if (rem < 96) {
      float sum = pacc[idx] + pacc[idx + 808] + pacc[idx + 1616] + pacc[idx + 2424];
      atomicAdd(&protoAcc[c8 * 96 + rem], sum);
    }
  }
}

// ---------------------------------------------------------------------------
// k_place + inline scan (R14-proven). Per block: exclusive prefix of
// blockCnt[ctr][0..blk-1]; block 0 writes counts[16]. Bit-identical to k_scan.
__global__ __launch_bounds__(256) void k_place(const unsigned char* __restrict__ flags,
                                               const int* __restrict__ blockCnt,
                                               int* __restrict__ tblV, int* __restrict__ tblH,
                                               int* __restrict__ counts) {
  __shared__ int wcnt[4][16];
  __shared__ int sOff[16], sTot[16];
  int tid = threadIdx.x;
  int blk = blockIdx.x;
  if (tid < 16) { sOff[tid] = 0; sTot[tid] = 0; }
  __syncthreads();
  {
    int ctr = tid & 15, seg = tid >> 4;              // 16 segs x 64 entries
    const int* row = blockCnt + ctr * NBLK + seg * 64;
    int lim = blk - seg * 64;                        // j < blk  <=>  l < lim
    int pre = 0, tot = 0;
    #pragma unroll 8
    for (int l = 0; l < 64; ++l) {
      int v = row[l];
      tot += v;
      pre += (l < lim) ? v : 0;
    }
    atomicAdd(&sOff[ctr], pre);
    if (blk == 0) atomicAdd(&sTot[ctr], tot);
  }
  __syncthreads();
  if (blk == 0 && tid < 16) counts[tid] = sTot[tid];
  // ---------------- original place body ----------------
  int n = blk * 256 + tid;
  int f = flags[n];
  int cls = f & 15; bool v = (f & 16) != 0, h = (f & 32) != 0;
  int wave = tid >> 6, lane = tid & 63;
  unsigned long long below = (1ull << lane) - 1ull;
  int rv = 0, rh = 0;
  for (int s = 0; s < 8; s++) {
    unsigned long long bv = __ballot(v && (cls == s));
    unsigned long long bh = __ballot(h && (cls == s));
    if (lane == 0) { wcnt[wave][s] = __popcll(bv); wcnt[wave][8 + s] = __popcll(bh); }
    if (cls == s) { rv = __popcll(bv & below); rh = __popcll(bh & below); }
  }
  __syncthreads();
  int preV = 0, preH = 0;
  for (int w2 = 0; w2 < wave; w2++) { preV += wcnt[w2][cls]; preH += wcnt[w2][8 + cls]; }
  if (v) tblV[(size_t)cls * NPIX + sOff[cls] + preV + rv] = n;
  if (h) tblH[(size_t)cls * NPIX + sOff[8 + cls] + preH + rh] = n;
}

// finalize prototypes + inter-prototype MLS logits; packed f16 protoPQ (R8, proven)
__global__ void k_protoFinal(const float* __restrict__ protoAcc, const int* __restrict__ counts,
                             u32* __restrict__ protoPQ, float* __restrict__ simL,
                             int* __restrict__ diag) {
  __shared__ float sP[256], sQ[256];
  __shared__ int alive;
  int tid = threadIdx.x;
  if (tid == 0) alive = 0;
  float a0 = protoAcc[tid * 3 + 0], a1 = protoAcc[tid * 3 + 1], a2 = protoAcc[tid * 3 + 2];
  bool have = counts[tid >> 5] > 0;
  bool ok = (a0 > 0.f) && (a2 > 0.f);
  __syncthreads();
  if (have && !ok) atomicOr(diag, 2);
  if (have && ok) alive = 1;
  float psig = 1.0f / a0;
  float pmu  = psig * a1;
  float pw   = 1.0f / a2;
  float sq = (have && ok) ? pmu * pmu : 0.f;
  #pragma unroll
  for (int d = 1; d < 32; d <<= 1) sq += __shfl_xor(sq, d);
  float rn = 1.0f / fmaxf(sqrtf(sq), 1e-12f);
  float pP = (have && ok) ? pmu * rn * pw : 0.f;
  float pQ = (have && ok) ? psig * pw : 0.f;
  sP[tid] = pP; sQ[tid] = pQ;
  protoPQ[tid] = packPQ(pP, pQ);
  __syncthreads();
  if (tid == 0 && alive == 0) atomicOr(diag, 32);
  if (tid < 64) {
    int i = tid >> 3, j = tid & 7;
    if (j < 7) {
      int o = (i + 1 + j) & 7;
      float acc = 0.f;
      for (int c = 0; c < 32; c++) {
        float d = sP[i * 32 + c] - sP[o * 32 + c];
        float dn = sQ[i * 32 + c] + sQ[o * 32 + c];
        acc += d * d / dn + logf(dn);
      }
      float sim = -0.5f * (acc * (1.0f / 32.0f));
      simL[i * 8 + j] = (counts[o] > 0) ? (sim * 2.0f) : -INFINITY;  // /TEMP(0.5)
    }
  }
}

// ---- R11 k_sample (proven 42.0us): anchor redundant on all threads; A-row
// direct from global (wave-uniform broadcast); fast __logf gumbel; rcp-mul MLS.
__global__ __launch_bounds__(256) void k_sample(TFKeys K, const float* __restrict__ simL,
                                                const int* __restrict__ counts,
                                                const int* __restrict__ tblV, const int* __restrict__ tblH,
                                                const u32* __restrict__ PQ, const u32* __restrict__ protoPQ,
                                                float* __restrict__ ceAcc, int* __restrict__ diag) {
  __shared__ float redM[4], redS[4];
  int blk = blockIdx.x;
  int i = blk >> 8, q = blk & 255;
  int t = threadIdx.x;
  u32 abits = rbits(K.k1[i][0], K.k1[i][1], (u32)q);
  float au = u01(abits);
  int hc = counts[8 + i];
  int ra = (int)(au * (float)hc);
  int cap = hc - 1; if (cap < 0) cap = 0;
  if (ra > cap) ra = cap; if (ra < 0) ra = 0;
  int ap = tblH[(size_t)i * NPIX + ra];
  if (ap < 0) ap = 0; if (ap > NPIX - 1) ap = NPIX - 1;
  const uint4* A4 = (const uint4*)(PQ + (size_t)ap * 32);
  u32 rem = (u32)(q * 256 + t);
  u32 k20 = K.k2[i][0], k21 = K.k2[i][1];
  float Lr[7];
  #pragma unroll
  for (int j = 0; j < 7; j++) Lr[j] = simL[i * 8 + j];
  float mg = 0.f; int pick = 0;
  #pragma unroll
  for (int j = 0; j < 7; j++) {
    u32 bits = rbits(k20, k21, rem * 7u + (u32)j);
    float f = u01(bits);
    float u = fmaxf(f, 1.17549435e-38f);
    float g = -__logf(-__logf(u));
    float v = g + Lr[j];
    if (j == 0) { mg = v; } else if (v > mg) { mg = v; pick = j; }
  }
  int nc = (i + 1 + pick) & 7;
  u32 bits3 = rbits(K.k3[i][0], K.k3[i][1], rem);
  float u3 = u01(bits3);
  int cntv = counts[nc];
  int rn = (int)(u3 * (float)cntv);
  int cap2 = cntv - 1; if (cap2 < 0) cap2 = 0;
  if (rn > cap2) rn = cap2; if (rn < 0) rn = 0;
  int np = tblV[(size_t)nc * NPIX + rn];
  if (np < 0) np = 0; if (np > NPIX - 1) np = NPIX - 1;
  const uint4* B = (const uint4*)(PQ + (size_t)np * 32);
  float accN = 0.f;
  #pragma unroll
  for (int k = 0; k < 8; k++) {
    uint4 ua = A4[k], ub = B[k];
    float2 fa, fb; float d, dn;
    fa = unpackPQ(ua.x); fb = unpackPQ(ub.x); d = fa.x - fb.x; dn = fa.y + fb.y; accN += d * d * frcp(dn) + __logf(dn);
    fa = unpackPQ(ua.y); fb = unpackPQ(ub.y); d = fa.x - fb.x; dn = fa.y + fb.y; accN += d * d * frcp(dn) + __logf(dn);
    fa = unpackPQ(ua.z); fb = unpackPQ(ub.z); d = fa.x - fb.x; dn = fa.y + fb.y; accN += d * d * frcp(dn) + __logf(dn);
    fa = unpackPQ(ua.w); fb = unpackPQ(ub.w); d = fa.x - fb.x; dn = fa.y + fb.y; accN += d * d * frcp(dn) + __logf(dn);
  }
  float lN = -(accN * (1.0f / 32.0f));
  float l0 = 0.f;
  if (t == 0) {
    const uint4* B0 = (const uint4*)(protoPQ + i * 32);
    float acc0 = 0.f;
    #pragma unroll
    for (int k = 0; k < 8; k++) {
      uint4 ua = A4[k], ub = B0[k];
      float2 fa, fb; float d, dn;
      fa = unpackPQ(ua.x); fb = unpackPQ(ub.x); d = fa.x - fb.x; dn = fa.y + fb.y; acc0 += d * d * frcp(dn) + __logf(dn);
      fa = unpackPQ(ua.y); fb = unpackPQ(ub.y); d = fa.x - fb.x; dn = fa.y + fb.y; acc0 += d * d * frcp(dn) + __logf(dn);
      fa = unpackPQ(ua.z); fb = unpackPQ(ub.z); d = fa.x - fb.x; dn = fa.y + fb.y; acc0 += d * d * frcp(dn) + __logf(dn);
      fa = unpackPQ(ua.w); fb = unpackPQ(ub.w); d = fa.x - fb.x; dn = fa.y + fb.y; acc0 += d * d * frcp(dn) + __logf(dn);
    }
    l0 = -(acc0 * (1.0f / 32.0f));
  }
  bool bad = !(lN == lN) || (t == 0 && !(l0 == l0));
  if (__ballot(bad) != 0ull && (t & 63) == 0) atomicOr(diag, 8);
  float lm = (t == 0) ? fmaxf(lN, l0) : lN;
  #pragma unroll
  for (int d = 1; d < 64; d <<= 1) lm = fmaxf(lm, __shfl_xor(lm, d));
  if ((t & 63) == 0) redM[t >> 6] = lm;
  __syncthreads();
  float M = fmaxf(fmaxf(redM[0], redM[1]), fmaxf(redM[2], redM[3]));
  float es = __expf(lN - M) + ((t == 0) ? __expf(l0 - M) : 0.f);
  #pragma unroll
  for (int d = 1; d < 64; d <<= 1) es += __shfl_xor(es, d);
  if ((t & 63) == 0) redS[t >> 6] = es;
  __syncthreads();
  if (t == 0) {
    float S = redS[0] + redS[1] + redS[2] + redS[3];
    float ce = (M + __logf(S)) - l0;
    atomicAdd(&ceAcc[i], ce);
  }
}

__global__ void k_final(const float* __restrict__ ceAcc, const int* __restrict__ counts,
                        const int* __restrict__ diag, u32* __restrict__ out) {
  if (blockIdx.x == 0 && threadIdx.x == 0) {
    float loss = 0.f; int vn = 0;
    int db = diag[0];
    for (int i = 0; i < 8; i++) {
      if (counts[i] > 0) vn++;
      float ce = ceAcc[i];
      if (counts[i] > 0 && counts[8 + i] > 0) {
        if (!(ce == ce)) db |= 4;
        loss += ce * (1.0f / 256.0f);
      }
    }
    if (vn == 0) db |= 1;
    loss = loss / (float)vn;
    if (!(loss == loss) && db == 0) db = 16;
    if (db != 0) loss = 4096.0f * (float)(1 + db);
    u32 fb = __float_as_uint(loss);
    u32 bv = (fb + 0x7FFFu + ((fb >> 16) & 1u)) >> 16;          // f32 -> bf16 RNE
    out[0] = (fb & 0xFFFF0000u) | (bv & 0xFFFFu);               // dual-decodable
  }
}

// ---------------------------------------------------------------------------
extern "C" void kernel_launch(void* const* d_in, const int* in_sizes, int n_in,
                              void* d_out, int out_size, void* d_ws, size_t ws_size,
                              hipStream_t stream) {
  (void)in_sizes; (void)n_in; (void)out_size; (void)ws_size;
  const u16* wgt = (const u16*)d_in[0];
  const u16* mu  = (const u16*)d_in[1];
  const u16* sig = (const u16*)d_in[2];
  const u16* lab = (const u16*)d_in[3];
  const u16* msk = (const u16*)d_in[4];
  const u16* prb = (const u16*)d_in[5];

  // workspace carve (256B-aligned); total ~49 MB
  char* wp = (char*)d_ws;
  auto take = [&](size_t bytes) -> void* { void* p = (void*)wp; wp += ((bytes + 255) & ~(size_t)255); return p; };
  u32*   PQ       = (u32*)  take((size_t)NPIX * 32 * 4);
  int*   tblV     = (int*)  take((size_t)NCLS * NPIX * 4);
  int*   tblH     = (int*)  take((size_t)NCLS * NPIX * 4);
  unsigned char* flags = (unsigned char*)take(NPIX);
  int*   blockCnt = (int*)  take(16 * NBLK * 4);
  float* protoAcc = (float*)take(768 * 4);
  u32*   protoPQ  = (u32*)  take(256 * 4);
  float* simL     = (float*)take(64 * 4);
  int*   counts   = (int*)  take(16 * 4);
  float* ceAcc    = (float*)take(8 * 4);
  int*   diag     = (int*)  take(4);

  // Host-side JAX key derivation (partitionable/fold-like split)
  TFKeys K;
  for (u32 i = 0; i < 8; i++) {
    u32 ki0, ki1;
    tf2x32(0u, 42u, 0u, i, ki0, ki1);
    tf2x32(ki0, ki1, 0u, 0u, K.k1[i][0], K.k1[i][1]);
    tf2x32(ki0, ki1, 0u, 1u, K.k2[i][0], K.k2[i][1]);
    tf2x32(ki0, ki1, 0u, 2u, K.k3[i][0], K.k3[i][1]);
  }

  k_flags<<<1024, 256, 0, stream>>>(lab, msk, prb, flags, blockCnt, protoAcc, ceAcc, diag);
  k_pq_proto<<<512, 256, 0, stream>>>(mu, wgt, sig, flags, PQ, protoAcc);
  k_place<<<1024, 256, 0, stream>>>(flags, blockCnt, tblV, tblH, counts);
  k_protoFinal<<<1, 256, 0, stream>>>(protoAcc, counts, protoPQ, simL, diag);
  k_sample<<<2048, 256, 0, stream>>>(K, simL, counts, tblV, tblH, PQ, protoPQ, ceAcc, diag);
  k_final<<<1, 64, 0, stream>>>(ceAcc, counts, diag, (u32*)d_out);
}